// Round 11
// baseline (123.593 us; speedup 1.0000x reference)
//
#include <hip/hip_runtime.h>
#include <hip/hip_bf16.h>

#define N_ENT 100000
#define NB 16
#define DIM 128
#define TILE 64
#define NWAVE 8
#define N_TILES ((N_ENT + TILE - 1) / TILE)   // 1563

// ---------------- kernel 1: head = normalize(ent[e1]) + normalize(rel[r]) ----
__global__ __launch_bounds__(128) void head_kernel(
    const int* __restrict__ e1, const int* __restrict__ rel,
    const float* __restrict__ ent, const float* __restrict__ relemb,
    float* __restrict__ head)
{
    int b = blockIdx.x, d = threadIdx.x;
    float ev = ent[e1[b] * DIM + d];
    float rv = relemb[rel[b] * DIM + d];
    __shared__ float s1[DIM], s2[DIM];
    s1[d] = ev * ev;
    s2[d] = rv * rv;
    __syncthreads();
    for (int s = 64; s > 0; s >>= 1) {
        if (d < s) { s1[d] += s1[d + s]; s2[d] += s2[d + s]; }
        __syncthreads();
    }
    float ne = fmaxf(sqrtf(s1[0]), 1e-12f);
    float nr = fmaxf(sqrtf(s2[0]), 1e-12f);
    head[b * DIM + d] = ev / ne + rv / nr;
}

// ---------------- kernel 2: k-split dist + exp ------------------------------
// 1563 blocks, one 64-entity tile each; block = 8 waves. Wave w owns j-slice
// [4w,4w+4) (16 floats) of ALL 64 rows, held in VGPRs (loaded directly from
// global: lane = entity, 64B/lane; waves 2k,2k+1 consume complementary
// halves of each 128B line -> no overfetch). Each wave computes all 16 b's
// over its slice (acc[16] VGPRs). Row data is NEVER re-read: LDS is used
// only for the tiny cross-wave reductions (ssq 2KB + partials 32KB).
__global__ __launch_bounds__(512, 8) void dist_kernel(
    const float* __restrict__ ent, const float* __restrict__ head,
    float* __restrict__ partials, float* __restrict__ out)
{
    __shared__ float ldsSsq[NWAVE][TILE];        // 2048 B
    __shared__ float ldsPart[NWAVE][NB][TILE];   // 32768 B

    const int tid  = threadIdx.x;
    const int lane = tid & 63;
    const int wv   = __builtin_amdgcn_readfirstlane(tid >> 6);  // uniform 0..7
    const int n0   = blockIdx.x * TILE;
    int gr = n0 + lane;
    if (gr >= N_ENT) gr = N_ENT - 1;             // clamp for partial last tile

    // phase A: load my 16-float j-slice of row 'lane' into VGPRs + slice ssq
    const float4* __restrict__ eg = (const float4*)ent;
    float4 seg[4];
    float ssq = 0.f;
    #pragma unroll
    for (int c = 0; c < 4; c++) {
        seg[c] = eg[gr * 32 + wv * 4 + c];
        ssq = fmaf(seg[c].x, seg[c].x, ssq);
        ssq = fmaf(seg[c].y, seg[c].y, ssq);
        ssq = fmaf(seg[c].z, seg[c].z, ssq);
        ssq = fmaf(seg[c].w, seg[c].w, ssq);
    }
    ldsSsq[wv][lane] = ssq;
    __syncthreads();                             // barrier 1

    // full-row inv norm (every lane sums the 8 slice-ssqs of its entity)
    float t = 0.f;
    #pragma unroll
    for (int w = 0; w < NWAVE; w++) t += ldsSsq[w][lane];
    const float inv = 1.0f / fmaxf(sqrtf(t), 1e-12f);

    // phase B: partial L1 distance over my slice, all 16 b's
    const float4* __restrict__ hg = (const float4*)head;  // uniform-indexed
    float acc[NB];
    #pragma unroll
    for (int b = 0; b < NB; b++) acc[b] = 0.f;
    #pragma unroll
    for (int c = 0; c < 4; c++) {
        const float4 v = seg[c];
        const int jg = wv * 4 + c;               // uniform
        #pragma unroll
        for (int b = 0; b < NB; b++) {
            float4 q = hg[b * 32 + jg];          // uniform -> scalar load
            acc[b] += fabsf(fmaf(-v.x, inv, q.x)) + fabsf(fmaf(-v.y, inv, q.y))
                    + fabsf(fmaf(-v.z, inv, q.z)) + fabsf(fmaf(-v.w, inv, q.w));
        }
    }

    // phase C: publish my 16 partials (bank-conflict-free: addr varies by lane)
    #pragma unroll
    for (int b = 0; b < NB; b++) ldsPart[wv][b][lane] = acc[b];
    __syncthreads();                             // barrier 2

    // phase D: wave w finalizes b = 2w, 2w+1 for all 64 entities
    const int b0 = 2 * wv, b1 = b0 + 1;
    float s0 = 0.f, s1 = 0.f;
    #pragma unroll
    for (int w = 0; w < NWAVE; w++) {
        s0 += ldsPart[w][b0][lane];
        s1 += ldsPart[w][b1][lane];
    }
    // exp; no max-subtract needed: dist <= 34, sums < 6e19 << fp32 max
    const int n = n0 + lane;
    const bool valid = (n < N_ENT);
    float e0 = valid ? __expf(s0) : 0.f;
    float e1 = valid ? __expf(s1) : 0.f;
    if (valid) {
        out[b0 * N_ENT + n] = e0;                // lane-contiguous: coalesced
        out[b1 * N_ENT + n] = e1;
    }
#define WRED(x) { x += __shfl_down(x, 32); x += __shfl_down(x, 16); \
                  x += __shfl_down(x, 8);  x += __shfl_down(x, 4);  \
                  x += __shfl_down(x, 2);  x += __shfl_down(x, 1); }
    WRED(e0) WRED(e1)
#undef WRED
    if (lane == 0) {   // b-major: partials[b*N_TILES + block] — no contention
        partials[b0 * N_TILES + blockIdx.x] = e0;
        partials[b1 * N_TILES + blockIdx.x] = e1;
    }
}

// ---------------- kernel 3: out *= 1/sum(partials[b][*]) --------------------
// Each block redundantly reduces its row's 1563 partials (6.3 KB, L2-hot).
__global__ __launch_bounds__(256) void scale_kernel(
    float* __restrict__ out, const float* __restrict__ partials)
{
    const int b = blockIdx.y;
    const int tid = threadIdx.x;

    // load my output chunk first (overlaps with the reduction)
    const int i = blockIdx.x * 256 + tid;              // float4 index
    float4 v = make_float4(0.f, 0.f, 0.f, 0.f);
    float4* row = (float4*)&out[b * N_ENT];
    const bool valid = (i < N_ENT / 4);
    if (valid) v = row[i];

    float s = 0.f;
    for (int k = tid; k < N_TILES; k += 256) s += partials[b * N_TILES + k];
    s += __shfl_down(s, 32); s += __shfl_down(s, 16);
    s += __shfl_down(s, 8);  s += __shfl_down(s, 4);
    s += __shfl_down(s, 2);  s += __shfl_down(s, 1);
    __shared__ float red[4];
    if ((tid & 63) == 0) red[tid >> 6] = s;
    __syncthreads();
    const float invS = 1.0f / (red[0] + red[1] + red[2] + red[3]);

    if (valid) {
        v.x *= invS; v.y *= invS; v.z *= invS; v.w *= invS;
        row[i] = v;
    }
}

extern "C" void kernel_launch(void* const* d_in, const int* in_sizes, int n_in,
                              void* d_out, int out_size, void* d_ws, size_t ws_size,
                              hipStream_t stream) {
    const int*   e1     = (const int*)d_in[0];
    const int*   rel    = (const int*)d_in[1];
    const float* ent    = (const float*)d_in[4];
    const float* relemb = (const float*)d_in[5];
    float* out = (float*)d_out;

    float* head     = (float*)d_ws;                    // 16*128 f32 = 8192 B
    float* partials = (float*)((char*)d_ws + 8192);    // 16*1563 f32 = 100032 B
    // every partials slot is written before it is read -> no zeroing needed

    head_kernel<<<16, 128, 0, stream>>>(e1, rel, ent, relemb, head);
    dist_kernel<<<N_TILES, 512, 0, stream>>>(ent, head, partials, out);
    scale_kernel<<<dim3((N_ENT / 4 + 255) / 256, NB), 256, 0, stream>>>(out, partials);
}

// Round 12
// 122.413 us; speedup vs baseline: 1.0096x; 1.0096x over previous
//
#include <hip/hip_runtime.h>
#include <hip/hip_bf16.h>

#define N_ENT 100000
#define NB 16
#define DIM 128
#define TILE 64
#define RSTRIDE 132      // 128+4 floats: per-lane reads conflict-light (r9-proven)
#define NWAVE 8
#define N_TILES ((N_ENT + TILE - 1) / TILE)   // 1563

// ---------------- kernel 1: head = normalize(ent[e1]) + normalize(rel[r]) ----
__global__ __launch_bounds__(128) void head_kernel(
    const int* __restrict__ e1, const int* __restrict__ rel,
    const float* __restrict__ ent, const float* __restrict__ relemb,
    float* __restrict__ head)
{
    int b = blockIdx.x, d = threadIdx.x;
    float ev = ent[e1[b] * DIM + d];
    float rv = relemb[rel[b] * DIM + d];
    __shared__ float s1[DIM], s2[DIM];
    s1[d] = ev * ev;
    s2[d] = rv * rv;
    __syncthreads();
    for (int s = 64; s > 0; s >>= 1) {
        if (d < s) { s1[d] += s1[d + s]; s2[d] += s2[d + s]; }
        __syncthreads();
    }
    float ne = fmaxf(sqrtf(s1[0]), 1e-12f);
    float nr = fmaxf(sqrtf(s2[0]), 1e-12f);
    head[b * DIM + d] = ev / ne + rv / nr;
}

// ---------------- kernel 2: k-split dist, slices staged through LDS ---------
// 1563 blocks, one 64-entity tile; block = 8 waves. Phase A: COALESCED stage
// into padded LDS + ssq fused from staging regs. Phase B: lane (=entity)
// pulls its wave's 16-float j-slice into VGPRs (4 ds_read_b128), then the
// j-loop is PURE VALU (regs + uniform s_load heads) — zero LDS, zero
// addressing in the hot loop. Phase C/D: acc[16] partials cross-reduced via
// LDS (overlaying the row buffer -> total 34 KB, 4 blocks/CU, 32 waves/CU);
// wave w finalizes b=2w,2w+1. This isolates the stall-vs-VALU question:
// the r11 k-split idea with the uncoalesced-load flaw fixed.
__global__ __launch_bounds__(512, 8) void dist_kernel(
    const float* __restrict__ ent, const float* __restrict__ head,
    float* __restrict__ partials, float* __restrict__ out)
{
    __shared__ float lds[TILE * RSTRIDE + TILE];   // 34048 B
    float* ldsRow = lds;
    float* ldsInv = lds + TILE * RSTRIDE;
    float (*ldsPart)[NB][TILE] = (float (*)[NB][TILE])lds;  // overlay (8192 f)

    const int tid  = threadIdx.x;
    const int lane = tid & 63;
    const int wv   = __builtin_amdgcn_readfirstlane(tid >> 6);  // uniform 0..7
    const int n0   = blockIdx.x * TILE;

    // phase A: coalesced stage + fused ssq (thread owns row tid>>3, 8 thr/row)
    {
        const float4* __restrict__ eg = (const float4*)ent;
        int r = tid >> 3, q = tid & 7;
        int gr = n0 + r;
        if (gr >= N_ENT) gr = N_ENT - 1;       // clamp for partial last tile
        float ssq = 0.f;
        #pragma unroll
        for (int i = 0; i < 4; i++) {
            int c = q + 8 * i;
            float4 v = eg[gr * 32 + c];
            ssq = fmaf(v.x, v.x, fmaf(v.y, v.y, fmaf(v.z, v.z, fmaf(v.w, v.w, ssq))));
            *(float4*)&ldsRow[r * RSTRIDE + c * 4] = v;
        }
        ssq += __shfl_down(ssq, 4);            // 8 threads/row, same wave
        ssq += __shfl_down(ssq, 2);
        ssq += __shfl_down(ssq, 1);
        if (q == 0) ldsInv[r] = 1.0f / fmaxf(sqrtf(ssq), 1e-12f);
    }
    __syncthreads();                           // barrier 1: rows + inv ready

    // phase B: my j-slice -> VGPRs, then VALU-only j-loop over all 16 b
    const float inv = ldsInv[lane];
    float4 seg[4];
    #pragma unroll
    for (int c = 0; c < 4; c++)
        seg[c] = *(const float4*)&ldsRow[lane * RSTRIDE + (wv * 4 + c) * 4];

    const float4* __restrict__ hg = (const float4*)head;  // uniform-indexed
    float acc[NB];
    #pragma unroll
    for (int b = 0; b < NB; b++) acc[b] = 0.f;
    #pragma unroll
    for (int c = 0; c < 4; c++) {
        const float4 v = seg[c];
        const int jg = wv * 4 + c;             // uniform
        #pragma unroll
        for (int b = 0; b < NB; b++) {
            float4 q = hg[b * 32 + jg];        // uniform -> s_load_dwordx4
            acc[b] += fabsf(fmaf(-v.x, inv, q.x)) + fabsf(fmaf(-v.y, inv, q.y))
                    + fabsf(fmaf(-v.z, inv, q.z)) + fabsf(fmaf(-v.w, inv, q.w));
        }
    }
    __syncthreads();                           // barrier 2: rows consumed

    // phase C: publish acc[16] (lane-contiguous b32 -> conflict-free)
    #pragma unroll
    for (int b = 0; b < NB; b++) ldsPart[wv][b][lane] = acc[b];
    __syncthreads();                           // barrier 3

    // phase D: wave w finalizes b = 2w, 2w+1 for all 64 entities
    const int b0 = 2 * wv, b1 = b0 + 1;
    float s0 = 0.f, s1 = 0.f;
    #pragma unroll
    for (int w = 0; w < NWAVE; w++) {
        s0 += ldsPart[w][b0][lane];
        s1 += ldsPart[w][b1][lane];
    }
    // exp; no max-subtract needed: dist <= 34, sums < 6e19 << fp32 max
    const int n = n0 + lane;
    const bool valid = (n < N_ENT);
    float e0 = valid ? __expf(s0) : 0.f;
    float e1 = valid ? __expf(s1) : 0.f;
    if (valid) {
        out[b0 * N_ENT + n] = e0;              // lane-contiguous: coalesced
        out[b1 * N_ENT + n] = e1;
    }
#define WRED(x) { x += __shfl_down(x, 32); x += __shfl_down(x, 16); \
                  x += __shfl_down(x, 8);  x += __shfl_down(x, 4);  \
                  x += __shfl_down(x, 2);  x += __shfl_down(x, 1); }
    WRED(e0) WRED(e1)
#undef WRED
    if (lane == 0) {   // b-major: partials[b*N_TILES + block] — no contention
        partials[b0 * N_TILES + blockIdx.x] = e0;
        partials[b1 * N_TILES + blockIdx.x] = e1;
    }
}

// ---------------- kernel 3: out *= 1/sum(partials[b][*]) --------------------
// Each block redundantly reduces its row's 1563 partials (6.3 KB, L2-hot).
__global__ __launch_bounds__(256) void scale_kernel(
    float* __restrict__ out, const float* __restrict__ partials)
{
    const int b = blockIdx.y;
    const int tid = threadIdx.x;

    // load my output chunk first (overlaps with the reduction)
    const int i = blockIdx.x * 256 + tid;              // float4 index
    float4 v = make_float4(0.f, 0.f, 0.f, 0.f);
    float4* row = (float4*)&out[b * N_ENT];
    const bool valid = (i < N_ENT / 4);
    if (valid) v = row[i];

    float s = 0.f;
    for (int k = tid; k < N_TILES; k += 256) s += partials[b * N_TILES + k];
    s += __shfl_down(s, 32); s += __shfl_down(s, 16);
    s += __shfl_down(s, 8);  s += __shfl_down(s, 4);
    s += __shfl_down(s, 2);  s += __shfl_down(s, 1);
    __shared__ float red[4];
    if ((tid & 63) == 0) red[tid >> 6] = s;
    __syncthreads();
    const float invS = 1.0f / (red[0] + red[1] + red[2] + red[3]);

    if (valid) {
        v.x *= invS; v.y *= invS; v.z *= invS; v.w *= invS;
        row[i] = v;
    }
}

extern "C" void kernel_launch(void* const* d_in, const int* in_sizes, int n_in,
                              void* d_out, int out_size, void* d_ws, size_t ws_size,
                              hipStream_t stream) {
    const int*   e1     = (const int*)d_in[0];
    const int*   rel    = (const int*)d_in[1];
    const float* ent    = (const float*)d_in[4];
    const float* relemb = (const float*)d_in[5];
    float* out = (float*)d_out;

    float* head     = (float*)d_ws;                    // 16*128 f32 = 8192 B
    float* partials = (float*)((char*)d_ws + 8192);    // 16*1563 f32 = 100032 B
    // every partials slot is written before it is read -> no zeroing needed

    head_kernel<<<16, 128, 0, stream>>>(e1, rel, ent, relemb, head);
    dist_kernel<<<N_TILES, 512, 0, stream>>>(ent, head, partials, out);
    scale_kernel<<<dim3((N_ENT / 4 + 255) / 256, NB), 256, 0, stream>>>(out, partials);
}